// Round 8
// baseline (72.452 us; speedup 1.0000x reference)
//
#include <hip/hip_runtime.h>

// Problem constants (match reference)
#define HH 256
#define WW 256
#define NPIX (HH * WW)        // 65536
#define NP 512                // points
// ALPHA = -5.0, 1/ALPHA = -0.2

// term2 decomposition: each block = 4 consecutive points x one 32-row slice
#define PPB 4
#define SLICE_ROWS 32
#define NSLICES (HH / SLICE_ROWS)          // 8
#define NPGRP (NP / PPB)                   // 128
#define NB_T2 (NPGRP * NSLICES)            // 1024
#define NB_T1 (NPIX / 256)                 // 256
#define NB_TOTAL (NB_T1 + NB_T2)           // 1280

// ws float layout (NO memset: every slot read by final is written by main):
//   [0 .. 4096)          S-partials: ws[p*8 + slice]
//   [4096 .. 4352)       term1 v1 partials (per t1 block)
//   [4352 .. 4608)       term1 v2 partials
#define WS_SP   0
#define WS_T1A  (NP * NSLICES)             // 4096
#define WS_T1B  (WS_T1A + NB_T1)           // 4352

// ---- packed-f32 helpers: explicit 2-wide math so the compiler can emit
// v_pk_add_f32 / v_pk_mul_f32 / v_pk_fma_f32 (double-rate f32 on CDNA) ----
__device__ __forceinline__ float2 pk2(float a, float b) { return make_float2(a, b); }
__device__ __forceinline__ float2 pk_add(float2 a, float2 b) { return make_float2(a.x + b.x, a.y + b.y); }
__device__ __forceinline__ float2 pk_sub(float2 a, float2 b) { return make_float2(a.x - b.x, a.y - b.y); }
__device__ __forceinline__ float2 pk_mul(float2 a, float2 b) { return make_float2(a.x * b.x, a.y * b.y); }
__device__ __forceinline__ float2 pk_fma(float2 a, float2 b, float2 c) {
    return make_float2(fmaf(a.x, b.x, c.x), fmaf(a.y, b.y, c.y));
}
__device__ __forceinline__ float2 pk_min(float2 a, float2 b) {
    return make_float2(fminf(a.x, b.x), fminf(a.y, b.y));
}
__device__ __forceinline__ float2 pk_sqrt(float2 a) {
    return make_float2(__builtin_amdgcn_sqrtf(a.x), __builtin_amdgcn_sqrtf(a.y));
}
__device__ __forceinline__ float2 pk_rcp(float2 a) {
    return make_float2(__builtin_amdgcn_rcpf(a.x), __builtin_amdgcn_rcpf(a.y));
}

__global__ __launch_bounds__(256) void whd_main(const float* __restrict__ hm,
                                                const float* __restrict__ pts,
                                                float* __restrict__ ws) {
    const int tid = threadIdx.x;
    const int bid = blockIdx.x;
    __shared__ float sred[PPB][4];
    __shared__ float dred[4];

    if (bid < NB_T1) {
        // ---------------- term 1: heat-weighted min distance ----------------
        const int idx = bid * 256 + tid;
        const float fi = (float)(idx >> 8);
        const float fj = (float)(idx & (WW - 1));
        const float2 fi2 = pk2(fi, fi), fj2 = pk2(fj, fj);
        const float4* pts4 = (const float4*)pts;   // uniform idx -> SGPR loads
        // 4 packed min-accumulators = 8 independent chains
        float2 ma = pk2(3.4e38f, 3.4e38f), mb = ma, mc = ma, md = ma;
        #pragma unroll 4
        for (int i = 0; i < NP / 2; i += 4) {      // each float4 = 2 points (y,x,y,x)
            float4 q0 = pts4[i], q1 = pts4[i + 1], q2 = pts4[i + 2], q3 = pts4[i + 3];
            float2 dy, dx;
            dy = pk_sub(fi2, pk2(q0.x, q0.z)); dx = pk_sub(fj2, pk2(q0.y, q0.w));
            ma = pk_min(ma, pk_fma(dy, dy, pk_mul(dx, dx)));
            dy = pk_sub(fi2, pk2(q1.x, q1.z)); dx = pk_sub(fj2, pk2(q1.y, q1.w));
            mb = pk_min(mb, pk_fma(dy, dy, pk_mul(dx, dx)));
            dy = pk_sub(fi2, pk2(q2.x, q2.z)); dx = pk_sub(fj2, pk2(q2.y, q2.w));
            mc = pk_min(mc, pk_fma(dy, dy, pk_mul(dx, dx)));
            dy = pk_sub(fi2, pk2(q3.x, q3.z)); dx = pk_sub(fj2, pk2(q3.y, q3.w));
            md = pk_min(md, pk_fma(dy, dy, pk_mul(dx, dx)));
        }
        float2 mm = pk_min(pk_min(ma, mb), pk_min(mc, md));
        float mind = __builtin_amdgcn_sqrtf(fminf(mm.x, mm.y));
        float h  = hm[idx];
        float v1 = h * mind;
        float v2 = fabsf(h);
        #pragma unroll
        for (int off = 32; off; off >>= 1) {
            v1 += __shfl_down(v1, off, 64);
            v2 += __shfl_down(v2, off, 64);
        }
        if ((tid & 63) == 0) { sred[0][tid >> 6] = v1; sred[1][tid >> 6] = v2; }
        __syncthreads();
        if (tid == 0) ws[WS_T1A + bid] = sred[0][0] + sred[0][1] + sred[0][2] + sred[0][3];
        if (tid == 1) ws[WS_T1B + bid] = sred[1][0] + sred[1][1] + sred[1][2] + sred[1][3];
    } else {
        // ---------------- term 2: soft-min accumulation ----------------
        const int b2 = bid - NB_T1;
        // dmax per block (cheap): grid max is at a corner; d^2 separable.
        float m = 0.f;
        #pragma unroll
        for (int t = 0; t < 2; ++t) {
            int p = tid + t * 256;
            float py = pts[2 * p], px = pts[2 * p + 1];
            float my = fmaxf(py * py, (255.f - py) * (255.f - py));
            float mx = fmaxf(px * px, (255.f - px) * (255.f - px));
            m = fmaxf(m, my + mx);
        }
        #pragma unroll
        for (int off = 32; off; off >>= 1) m = fmaxf(m, __shfl_down(m, off, 64));
        if ((tid & 63) == 0) dred[tid >> 6] = m;
        __syncthreads();
        const float dmax = __builtin_amdgcn_sqrtf(
            fmaxf(fmaxf(dred[0], dred[1]), fmaxf(dred[2], dred[3])));
        const float2 dmax2 = pk2(dmax, dmax);

        const int pgrp  = b2 & (NPGRP - 1);
        const int slice = b2 >> 7;             // NPGRP = 128
        const int p0    = pgrp * PPB;

        float py[PPB], px[PPB];
        #pragma unroll
        for (int a = 0; a < PPB; ++a) {        // uniform -> SGPR loads
            py[a] = pts[2 * (p0 + a)];
            px[a] = pts[2 * (p0 + a) + 1];
        }

        // thread owns cols col0..col0+3 of rows {slice*32 + (tid>>6) + 4k}
        const float col0 = (float)((tid & 63) << 2);
        float2 dx2A[PPB], dx2B[PPB];
        #pragma unroll
        for (int a = 0; a < PPB; ++a) {
            float2 dA = pk2(col0 + 0.f - px[a], col0 + 1.f - px[a]);
            float2 dB = pk2(col0 + 2.f - px[a], col0 + 3.f - px[a]);
            dx2A[a] = pk_mul(dA, dA);
            dx2B[a] = pk_mul(dB, dB);
        }

        const float4* hm4 = (const float4*)hm;
        const int   gbase   = slice * (SLICE_ROWS * WW / 4) + tid;
        const float rowbase = (float)(slice * SLICE_ROWS + (tid >> 6));

        // hoist ALL hm loads: 8 outstanding global_load_dwordx4, one drain
        float4 h4s[8];
        #pragma unroll
        for (int k = 0; k < 8; ++k) h4s[k] = hm4[gbase + k * 256];

        float2 accA[PPB], accB[PPB];
        #pragma unroll
        for (int a = 0; a < PPB; ++a) { accA[a] = pk2(0.f, 0.f); accB[a] = pk2(0.f, 0.f); }

        const float2 one2 = pk2(1.f, 1.f);
        #pragma unroll
        for (int k = 0; k < 8; ++k) {
            const float4 h4 = h4s[k];
            const float row = rowbase + (float)(4 * k);
            const float2 hA = pk2(h4.x, h4.y), hB = pk2(h4.z, h4.w);
            const float2 ctA = pk_mul(pk_sub(one2, hA), dmax2);   // (1-h)*dmax
            const float2 ctB = pk_mul(pk_sub(one2, hB), dmax2);

            #pragma unroll
            for (int a = 0; a < PPB; ++a) {
                float dy = row - py[a];
                float2 dy2 = pk2(dy * dy, dy * dy);
                // packed: add -> sqrt(scalar trans) -> fma -> rcp -> mul -> mul -> fma
                float2 dA = pk_sqrt(pk_add(dy2, dx2A[a]));
                float2 dB = pk_sqrt(pk_add(dy2, dx2B[a]));
                float2 wA = pk_fma(hA, dA, ctA);
                float2 wB = pk_fma(hB, dB, ctB);
                float2 rA = pk_rcp(wA);
                float2 rB = pk_rcp(wB);
                float2 r2A = pk_mul(rA, rA), r2B = pk_mul(rB, rB);
                accA[a] = pk_fma(pk_mul(r2A, r2A), rA, accA[a]);  // += w^-5
                accB[a] = pk_fma(pk_mul(r2B, r2B), rB, accB[a]);
            }
        }

        // interleaved reduction: 4 independent shfl chains per round
        float v[PPB];
        #pragma unroll
        for (int a = 0; a < PPB; ++a)
            v[a] = (accA[a].x + accA[a].y) + (accB[a].x + accB[a].y);
        #pragma unroll
        for (int off = 32; off; off >>= 1) {
            #pragma unroll
            for (int a = 0; a < PPB; ++a) v[a] += __shfl_down(v[a], off, 64);
        }
        if ((tid & 63) == 0) {
            #pragma unroll
            for (int a = 0; a < PPB; ++a) sred[a][tid >> 6] = v[a];
        }
        __syncthreads();
        if (tid < PPB) {
            ws[WS_SP + (p0 + tid) * NSLICES + slice] =
                sred[tid][0] + sred[tid][1] + sred[tid][2] + sred[tid][3];
        }
    }
}

// ---------------------------------------------------------------------------
// Final combine (1 block): kernel boundary guarantees visibility of partials.
// ---------------------------------------------------------------------------
__global__ __launch_bounds__(NP) void whd_final(const float* __restrict__ ws,
                                                float* __restrict__ out) {
    const int t = threadIdx.x;  // 0..511
    const float4* w4 = (const float4*)(ws + WS_SP);
    float4 a = w4[t * 2], b = w4[t * 2 + 1];
    float S = ((a.x + a.y) + (a.z + a.w)) + ((b.x + b.y) + (b.z + b.w));
    // soft_min[p] = (S/NPIX)^(-1/5) = exp2(-0.2*log2(S/NPIX))
    float sm = exp2f(-0.2f * log2f(S * (1.f / (float)NPIX)));
    float v1 = (t < NB_T1) ? ws[WS_T1A + t] : 0.f;
    float v2 = (t < NB_T1) ? ws[WS_T1B + t] : 0.f;

    #pragma unroll
    for (int off = 32; off; off >>= 1) {
        sm += __shfl_down(sm, off, 64);
        v1 += __shfl_down(v1, off, 64);
        v2 += __shfl_down(v2, off, 64);
    }
    __shared__ float red[3][8];
    if ((t & 63) == 0) { int w = t >> 6; red[0][w] = sm; red[1][w] = v1; red[2][w] = v2; }
    __syncthreads();
    if (t == 0) {
        float rsm = 0.f, r1 = 0.f, r2 = 0.f;
        #pragma unroll
        for (int w = 0; w < 8; ++w) { rsm += red[0][w]; r1 += red[1][w]; r2 += red[2][w]; }
        out[0] = r1 / r2 + rsm * (1.f / (float)NP);
    }
}

extern "C" void kernel_launch(void* const* d_in, const int* in_sizes, int n_in,
                              void* d_out, int out_size, void* d_ws, size_t ws_size,
                              hipStream_t stream) {
    const float* hm  = (const float*)d_in[0];   // (256,256) f32
    const float* pts = (const float*)d_in[1];   // (512,2)  f32
    float* ws  = (float*)d_ws;
    float* out = (float*)d_out;

    // no memset: every ws slot consumed by whd_final is written by whd_main
    whd_main <<<NB_TOTAL, 256, 0, stream>>>(hm, pts, ws);
    whd_final<<<1,        NP,  0, stream>>>(ws, out);
}

// Round 9
// 70.770 us; speedup vs baseline: 1.0238x; 1.0238x over previous
//
#include <hip/hip_runtime.h>

// Problem constants (match reference)
#define HH 256
#define WW 256
#define NPIX (HH * WW)        // 65536
#define NP 512                // points
// ALPHA = -5.0, 1/ALPHA = -0.2

// term2 decomposition: each block = 4 consecutive points x one 32-row slice
#define PPB 4
#define SLICE_ROWS 32
#define NSLICES (HH / SLICE_ROWS)          // 8
#define NPGRP (NP / PPB)                   // 128
#define NB_T2 (NPGRP * NSLICES)            // 1024
#define NB_T1 (NPIX / 256)                 // 256
#define NB_TOTAL (NB_T1 + NB_T2)           // 1280

// ws float layout (NO memset: every slot read by final is written by main):
//   [0 .. 4096)          S-partials: ws[p*8 + slice]
//   [4096 .. 4352)       term1 v1 partials (per t1 block)
//   [4352 .. 4608)       term1 v2 partials
#define WS_SP   0
#define WS_T1A  (NP * NSLICES)             // 4096
#define WS_T1B  (WS_T1A + NB_T1)           // 4352

// ---- genuine packed fp32 (VOP3P) via inline asm; f32x2 = VGPR pair ----
typedef float f32x2 __attribute__((ext_vector_type(2)));
__device__ __forceinline__ f32x2 pk_add(f32x2 a, f32x2 b) {
    f32x2 d; asm("v_pk_add_f32 %0, %1, %2" : "=v"(d) : "v"(a), "v"(b)); return d;
}
__device__ __forceinline__ f32x2 pk_mul(f32x2 a, f32x2 b) {
    f32x2 d; asm("v_pk_mul_f32 %0, %1, %2" : "=v"(d) : "v"(a), "v"(b)); return d;
}
__device__ __forceinline__ f32x2 pk_fma(f32x2 a, f32x2 b, f32x2 c) {
    f32x2 d; asm("v_pk_fma_f32 %0, %1, %2, %3" : "=v"(d) : "v"(a), "v"(b), "v"(c)); return d;
}

__global__ __launch_bounds__(256) void whd_main(const float* __restrict__ hm,
                                                const float* __restrict__ pts,
                                                float* __restrict__ ws) {
    const int tid = threadIdx.x;
    const int bid = blockIdx.x;
    __shared__ float sred[PPB][4];
    __shared__ float dmax_sh;

    if (bid < NB_T1) {
        // ---------------- term 1: heat-weighted min distance ----------------
        const int idx = bid * 256 + tid;
        const float fi = (float)(idx >> 8);
        const float fj = (float)(idx & (WW - 1));
        const float4* pts4 = (const float4*)pts;   // uniform idx -> SGPR loads
        float m0 = 3.4e38f, m1 = 3.4e38f, m2 = 3.4e38f, m3 = 3.4e38f;
        #pragma unroll 4
        for (int i = 0; i < NP / 2; i += 4) {      // each float4 = 2 points (y,x,y,x)
            float4 q0 = pts4[i], q1 = pts4[i + 1], q2 = pts4[i + 2], q3 = pts4[i + 3];
            float dy, dx;
            dy = fi - q0.x; dx = fj - q0.y; m0 = fminf(m0, fmaf(dy, dy, dx * dx));
            dy = fi - q0.z; dx = fj - q0.w; m1 = fminf(m1, fmaf(dy, dy, dx * dx));
            dy = fi - q1.x; dx = fj - q1.y; m2 = fminf(m2, fmaf(dy, dy, dx * dx));
            dy = fi - q1.z; dx = fj - q1.w; m3 = fminf(m3, fmaf(dy, dy, dx * dx));
            dy = fi - q2.x; dx = fj - q2.y; m0 = fminf(m0, fmaf(dy, dy, dx * dx));
            dy = fi - q2.z; dx = fj - q2.w; m1 = fminf(m1, fmaf(dy, dy, dx * dx));
            dy = fi - q3.x; dx = fj - q3.y; m2 = fminf(m2, fmaf(dy, dy, dx * dx));
            dy = fi - q3.z; dx = fj - q3.w; m3 = fminf(m3, fmaf(dy, dy, dx * dx));
        }
        float mind = __builtin_amdgcn_sqrtf(fminf(fminf(m0, m1), fminf(m2, m3)));
        float h  = hm[idx];
        float v1 = h * mind;
        float v2 = fabsf(h);
        #pragma unroll
        for (int off = 32; off; off >>= 1) {
            v1 += __shfl_down(v1, off, 64);
            v2 += __shfl_down(v2, off, 64);
        }
        if ((tid & 63) == 0) { sred[0][tid >> 6] = v1; sred[1][tid >> 6] = v2; }
        __syncthreads();
        if (tid == 0) ws[WS_T1A + bid] = sred[0][0] + sred[0][1] + sred[0][2] + sred[0][3];
        if (tid == 1) ws[WS_T1B + bid] = sred[1][0] + sred[1][1] + sred[1][2] + sred[1][3];
    } else {
        // ---------------- term 2: soft-min accumulation ----------------
        const int b2    = bid - NB_T1;
        const int pgrp  = b2 & (NPGRP - 1);
        const int slice = b2 >> 7;             // NPGRP = 128
        const int p0    = pgrp * PPB;

        // issue hm loads FIRST: latency hides under the dmax preamble
        const float4* hm4 = (const float4*)hm;
        const int gbase = slice * (SLICE_ROWS * WW / 4) + tid;
        float4 h4s[8];
        #pragma unroll
        for (int k = 0; k < 8; ++k) h4s[k] = hm4[gbase + k * 256];

        // dmax by wave 0 only (grid max is at a corner; d^2 separable);
        // other 3 waves just wait at the barrier (frees issue slots).
        if (tid < 64) {
            float m = 0.f;
            #pragma unroll
            for (int t = 0; t < 8; ++t) {
                int p = tid + t * 64;
                float py_ = pts[2 * p], px_ = pts[2 * p + 1];
                float my = fmaxf(py_ * py_, (255.f - py_) * (255.f - py_));
                float mx = fmaxf(px_ * px_, (255.f - px_) * (255.f - px_));
                m = fmaxf(m, my + mx);
            }
            #pragma unroll
            for (int off = 32; off; off >>= 1) m = fmaxf(m, __shfl_down(m, off, 64));
            if (tid == 0) dmax_sh = __builtin_amdgcn_sqrtf(m);
        }
        __syncthreads();
        const float dmax = dmax_sh;

        float py[PPB], px[PPB];
        #pragma unroll
        for (int a = 0; a < PPB; ++a) {        // uniform -> SGPR loads
            py[a] = pts[2 * (p0 + a)];
            px[a] = pts[2 * (p0 + a) + 1];
        }

        // thread owns cols col0..col0+3 of rows {slice*32 + (tid>>6) + 4k}
        const float col0 = (float)((tid & 63) << 2);
        f32x2 dx2A[PPB], dx2B[PPB];
        #pragma unroll
        for (int a = 0; a < PPB; ++a) {
            float d0 = col0 + 0.f - px[a], d1 = col0 + 1.f - px[a];
            float d2 = col0 + 2.f - px[a], d3 = col0 + 3.f - px[a];
            dx2A[a].x = d0 * d0; dx2A[a].y = d1 * d1;
            dx2B[a].x = d2 * d2; dx2B[a].y = d3 * d3;
        }

        const float rowbase = (float)(slice * SLICE_ROWS + (tid >> 6));
        f32x2 accA[PPB], accB[PPB];
        #pragma unroll
        for (int a = 0; a < PPB; ++a) {
            accA[a].x = 0.f; accA[a].y = 0.f;
            accB[a].x = 0.f; accB[a].y = 0.f;
        }

        #pragma unroll
        for (int k = 0; k < 8; ++k) {
            const float4 h4 = h4s[k];
            const float row = rowbase + (float)(4 * k);
            f32x2 hA;  hA.x = h4.x;  hA.y = h4.y;
            f32x2 hB;  hB.x = h4.z;  hB.y = h4.w;
            f32x2 ctA; ctA.x = fmaf(-h4.x, dmax, dmax); ctA.y = fmaf(-h4.y, dmax, dmax);
            f32x2 ctB; ctB.x = fmaf(-h4.z, dmax, dmax); ctB.y = fmaf(-h4.w, dmax, dmax);

            #pragma unroll
            for (int a = 0; a < PPB; ++a) {
                float dy  = row - py[a];
                float dy2 = dy * dy;
                f32x2 dy2p; dy2p.x = dy2; dy2p.y = dy2;
                f32x2 sA = pk_add(dy2p, dx2A[a]);
                f32x2 sB = pk_add(dy2p, dx2B[a]);
                f32x2 dA, dB;
                dA.x = __builtin_amdgcn_sqrtf(sA.x); dA.y = __builtin_amdgcn_sqrtf(sA.y);
                dB.x = __builtin_amdgcn_sqrtf(sB.x); dB.y = __builtin_amdgcn_sqrtf(sB.y);
                f32x2 wA = pk_fma(hA, dA, ctA);      // hm*d + (1-hm)*dmax
                f32x2 wB = pk_fma(hB, dB, ctB);
                // Montgomery batch inversion: 4 reciprocals from 1 v_rcp
                float p1 = wA.x * wA.y;
                float p2 = p1 * wB.x;
                float p3 = p2 * wB.y;
                float r  = __builtin_amdgcn_rcpf(p3);
                float i3 = r * p2;                   // 1/wB.y
                float q  = r * wB.y;                 // 1/p2
                float i2 = q * p1;                   // 1/wB.x
                float q2 = q * wB.x;                 // 1/p1
                f32x2 iA; iA.x = q2 * wA.y; iA.y = q2 * wA.x;   // 1/wA.x, 1/wA.y
                f32x2 iB; iB.x = i2;        iB.y = i3;
                f32x2 tA = pk_mul(iA, iA);
                f32x2 tB = pk_mul(iB, iB);
                accA[a] = pk_fma(pk_mul(tA, tA), iA, accA[a]);  // += w^-5
                accB[a] = pk_fma(pk_mul(tB, tB), iB, accB[a]);
            }
        }

        // interleaved reduction: 4 independent shfl chains per round
        float v[PPB];
        #pragma unroll
        for (int a = 0; a < PPB; ++a)
            v[a] = (accA[a].x + accA[a].y) + (accB[a].x + accB[a].y);
        #pragma unroll
        for (int off = 32; off; off >>= 1) {
            #pragma unroll
            for (int a = 0; a < PPB; ++a) v[a] += __shfl_down(v[a], off, 64);
        }
        if ((tid & 63) == 0) {
            #pragma unroll
            for (int a = 0; a < PPB; ++a) sred[a][tid >> 6] = v[a];
        }
        __syncthreads();
        if (tid < PPB) {
            ws[WS_SP + (p0 + tid) * NSLICES + slice] =
                sred[tid][0] + sred[tid][1] + sred[tid][2] + sred[tid][3];
        }
    }
}

// ---------------------------------------------------------------------------
// Final combine (1 block): kernel boundary guarantees visibility of partials.
// ---------------------------------------------------------------------------
__global__ __launch_bounds__(NP) void whd_final(const float* __restrict__ ws,
                                                float* __restrict__ out) {
    const int t = threadIdx.x;  // 0..511
    const float4* w4 = (const float4*)(ws + WS_SP);
    float4 a = w4[t * 2], b = w4[t * 2 + 1];
    float S = ((a.x + a.y) + (a.z + a.w)) + ((b.x + b.y) + (b.z + b.w));
    // soft_min[p] = (S/NPIX)^(-1/5) = exp2(-0.2*log2(S/NPIX))
    float sm = exp2f(-0.2f * log2f(S * (1.f / (float)NPIX)));
    float v1 = (t < NB_T1) ? ws[WS_T1A + t] : 0.f;
    float v2 = (t < NB_T1) ? ws[WS_T1B + t] : 0.f;

    #pragma unroll
    for (int off = 32; off; off >>= 1) {
        sm += __shfl_down(sm, off, 64);
        v1 += __shfl_down(v1, off, 64);
        v2 += __shfl_down(v2, off, 64);
    }
    __shared__ float red[3][8];
    if ((t & 63) == 0) { int w = t >> 6; red[0][w] = sm; red[1][w] = v1; red[2][w] = v2; }
    __syncthreads();
    if (t == 0) {
        float rsm = 0.f, r1 = 0.f, r2 = 0.f;
        #pragma unroll
        for (int w = 0; w < 8; ++w) { rsm += red[0][w]; r1 += red[1][w]; r2 += red[2][w]; }
        out[0] = r1 / r2 + rsm * (1.f / (float)NP);
    }
}

extern "C" void kernel_launch(void* const* d_in, const int* in_sizes, int n_in,
                              void* d_out, int out_size, void* d_ws, size_t ws_size,
                              hipStream_t stream) {
    const float* hm  = (const float*)d_in[0];   // (256,256) f32
    const float* pts = (const float*)d_in[1];   // (512,2)  f32
    float* ws  = (float*)d_ws;
    float* out = (float*)d_out;

    // no memset: every ws slot consumed by whd_final is written by whd_main
    whd_main <<<NB_TOTAL, 256, 0, stream>>>(hm, pts, ws);
    whd_final<<<1,        NP,  0, stream>>>(ws, out);
}

// Round 10
// 69.491 us; speedup vs baseline: 1.0426x; 1.0184x over previous
//
#include <hip/hip_runtime.h>

// Problem constants (match reference)
#define HH 256
#define WW 256
#define NPIX (HH * WW)        // 65536
#define NP 512                // points
// ALPHA = -5.0, 1/ALPHA = -0.2

// term2 decomposition: each block = 4 consecutive points x one 32-row slice
#define PPB 4
#define SLICE_ROWS 32
#define NSLICES (HH / SLICE_ROWS)          // 8
#define NPGRP (NP / PPB)                   // 128
#define NB_T2 (NPGRP * NSLICES)            // 1024
#define NB_T1 (NPIX / 256)                 // 256
#define NB_TOTAL (NB_T1 + NB_T2)           // 1280  (5 blocks/CU, all co-resident)

// ws float layout (NO memset: every slot read by final is written by main):
//   [0 .. 4096)          S-partials: ws[p*8 + slice]
//   [4096 .. 4352)       term1 v1 partials (per t1 block)
//   [4352 .. 4608)       term1 v2 partials
#define WS_SP   0
#define WS_T1A  (NP * NSLICES)             // 4096
#define WS_T1B  (WS_T1A + NB_T1)           // 4352

// launch_bounds(256, 5): 5 waves/EU minimum -> VGPR cap ~102. This is the
// key: the default (max-occupancy) allocator crushed us to 44 VGPRs, which
// forced the hm prefetch registers to be re-sunk into the loop (load-latency
// stall every k-iter). Grid is only 5 blocks/CU, so 5 waves/EU is all we need.
__global__ __launch_bounds__(256, 5) void whd_main(const float* __restrict__ hm,
                                                   const float* __restrict__ pts,
                                                   float* __restrict__ ws) {
    const int tid = threadIdx.x;
    const int bid = blockIdx.x;
    __shared__ float sred[PPB][4];
    __shared__ float dmax_sh;

    if (bid < NB_T1) {
        // ---------------- term 1: heat-weighted min distance ----------------
        const int idx = bid * 256 + tid;
        const float fi = (float)(idx >> 8);
        const float fj = (float)(idx & (WW - 1));
        const float4* pts4 = (const float4*)pts;   // uniform idx -> SGPR loads
        float m0 = 3.4e38f, m1 = 3.4e38f, m2 = 3.4e38f, m3 = 3.4e38f;
        #pragma unroll 4
        for (int i = 0; i < NP / 2; i += 4) {      // each float4 = 2 points (y,x)
            float4 q0 = pts4[i], q1 = pts4[i + 1], q2 = pts4[i + 2], q3 = pts4[i + 3];
            float dy, dx;
            dy = fi - q0.x; dx = fj - q0.y; m0 = fminf(m0, fmaf(dy, dy, dx * dx));
            dy = fi - q0.z; dx = fj - q0.w; m1 = fminf(m1, fmaf(dy, dy, dx * dx));
            dy = fi - q1.x; dx = fj - q1.y; m2 = fminf(m2, fmaf(dy, dy, dx * dx));
            dy = fi - q1.z; dx = fj - q1.w; m3 = fminf(m3, fmaf(dy, dy, dx * dx));
            dy = fi - q2.x; dx = fj - q2.y; m0 = fminf(m0, fmaf(dy, dy, dx * dx));
            dy = fi - q2.z; dx = fj - q2.w; m1 = fminf(m1, fmaf(dy, dy, dx * dx));
            dy = fi - q3.x; dx = fj - q3.y; m2 = fminf(m2, fmaf(dy, dy, dx * dx));
            dy = fi - q3.z; dx = fj - q3.w; m3 = fminf(m3, fmaf(dy, dy, dx * dx));
        }
        float mind = __builtin_amdgcn_sqrtf(fminf(fminf(m0, m1), fminf(m2, m3)));
        float h  = hm[idx];
        float v1 = h * mind;
        float v2 = fabsf(h);
        #pragma unroll
        for (int off = 32; off; off >>= 1) {
            v1 += __shfl_down(v1, off, 64);
            v2 += __shfl_down(v2, off, 64);
        }
        if ((tid & 63) == 0) { sred[0][tid >> 6] = v1; sred[1][tid >> 6] = v2; }
        __syncthreads();
        if (tid == 0) ws[WS_T1A + bid] = sred[0][0] + sred[0][1] + sred[0][2] + sred[0][3];
        if (tid == 1) ws[WS_T1B + bid] = sred[1][0] + sred[1][1] + sred[1][2] + sred[1][3];
    } else {
        // ---------------- term 2: soft-min accumulation ----------------
        const int b2    = bid - NB_T1;
        const int pgrp  = b2 & (NPGRP - 1);
        const int slice = b2 >> 7;             // NPGRP = 128
        const int p0    = pgrp * PPB;

        // 2-deep hm prefetch pipeline; first two issued BEFORE the dmax
        // preamble so the preamble (~1 us) hides their L2 latency.
        const float4* hm4 = (const float4*)hm;
        const int gbase = slice * (SLICE_ROWS * WW / 4) + tid;
        float4 cur = hm4[gbase];
        float4 nxt = hm4[gbase + 256];

        // dmax by wave 0 only (grid max is at a corner; d^2 separable)
        if (tid < 64) {
            float m = 0.f;
            #pragma unroll
            for (int t = 0; t < 8; ++t) {
                int p = tid + t * 64;
                float py_ = pts[2 * p], px_ = pts[2 * p + 1];
                float my = fmaxf(py_ * py_, (255.f - py_) * (255.f - py_));
                float mx = fmaxf(px_ * px_, (255.f - px_) * (255.f - px_));
                m = fmaxf(m, my + mx);
            }
            #pragma unroll
            for (int off = 32; off; off >>= 1) m = fmaxf(m, __shfl_down(m, off, 64));
            if (tid == 0) dmax_sh = __builtin_amdgcn_sqrtf(m);
        }
        __syncthreads();
        const float dmax = dmax_sh;

        float py[PPB], px[PPB];
        #pragma unroll
        for (int a = 0; a < PPB; ++a) {        // uniform -> SGPR loads
            py[a] = pts[2 * (p0 + a)];
            px[a] = pts[2 * (p0 + a) + 1];
        }

        // thread owns cols col0..col0+3 of rows {slice*32 + (tid>>6) + 4k}
        const float col0 = (float)((tid & 63) << 2);
        float dx2[PPB][4];
        #pragma unroll
        for (int a = 0; a < PPB; ++a)
            #pragma unroll
            for (int c = 0; c < 4; ++c) {
                float dx = col0 + (float)c - px[a];
                dx2[a][c] = dx * dx;
            }

        const float rowbase = (float)(slice * SLICE_ROWS + (tid >> 6));
        float acc[PPB] = {0.f, 0.f, 0.f, 0.f};

        #pragma unroll
        for (int k = 0; k < 8; ++k) {
            const float4 h4 = cur;
            cur = nxt;
            if (k < 6) nxt = hm4[gbase + (k + 2) * 256];   // prefetch k+2
            const float row = rowbase + (float)(4 * k);
            const float hx[4] = {h4.x, h4.y, h4.z, h4.w};
            float ct[4];
            #pragma unroll
            for (int c = 0; c < 4; ++c) ct[c] = fmaf(-hx[c], dmax, dmax); // (1-h)*dmax
            float dy2[PPB];
            #pragma unroll
            for (int a = 0; a < PPB; ++a) { float dy = row - py[a]; dy2[a] = dy * dy; }

            // 16 independent 7-op chains: add->sqrt->fma->rcp->mul->mul->fma
            #pragma unroll
            for (int a = 0; a < PPB; ++a) {
                #pragma unroll
                for (int c = 0; c < 4; ++c) {
                    float d  = __builtin_amdgcn_sqrtf(dy2[a] + dx2[a][c]);
                    float w  = fmaf(hx[c], d, ct[c]);          // hm*d + (1-hm)*dmax
                    float r  = __builtin_amdgcn_rcpf(w);
                    float r2 = r * r;
                    acc[a]   = fmaf(r2 * r2, r, acc[a]);       // += w^-5
                }
            }
        }

        // interleaved reduction: 4 independent shfl chains per round
        float v[PPB] = {acc[0], acc[1], acc[2], acc[3]};
        #pragma unroll
        for (int off = 32; off; off >>= 1) {
            #pragma unroll
            for (int a = 0; a < PPB; ++a) v[a] += __shfl_down(v[a], off, 64);
        }
        if ((tid & 63) == 0) {
            #pragma unroll
            for (int a = 0; a < PPB; ++a) sred[a][tid >> 6] = v[a];
        }
        __syncthreads();
        if (tid < PPB) {
            ws[WS_SP + (p0 + tid) * NSLICES + slice] =
                sred[tid][0] + sred[tid][1] + sred[tid][2] + sred[tid][3];
        }
    }
}

// ---------------------------------------------------------------------------
// Final combine (1 block): kernel boundary guarantees visibility of partials.
// ---------------------------------------------------------------------------
__global__ __launch_bounds__(NP) void whd_final(const float* __restrict__ ws,
                                                float* __restrict__ out) {
    const int t = threadIdx.x;  // 0..511
    const float4* w4 = (const float4*)(ws + WS_SP);
    float4 a = w4[t * 2], b = w4[t * 2 + 1];
    float S = ((a.x + a.y) + (a.z + a.w)) + ((b.x + b.y) + (b.z + b.w));
    // soft_min[p] = (S/NPIX)^(-1/5) = exp2(-0.2*log2(S/NPIX))
    float sm = exp2f(-0.2f * log2f(S * (1.f / (float)NPIX)));
    float v1 = (t < NB_T1) ? ws[WS_T1A + t] : 0.f;
    float v2 = (t < NB_T1) ? ws[WS_T1B + t] : 0.f;

    #pragma unroll
    for (int off = 32; off; off >>= 1) {
        sm += __shfl_down(sm, off, 64);
        v1 += __shfl_down(v1, off, 64);
        v2 += __shfl_down(v2, off, 64);
    }
    __shared__ float red[3][8];
    if ((t & 63) == 0) { int w = t >> 6; red[0][w] = sm; red[1][w] = v1; red[2][w] = v2; }
    __syncthreads();
    if (t == 0) {
        float rsm = 0.f, r1 = 0.f, r2 = 0.f;
        #pragma unroll
        for (int w = 0; w < 8; ++w) { rsm += red[0][w]; r1 += red[1][w]; r2 += red[2][w]; }
        out[0] = r1 / r2 + rsm * (1.f / (float)NP);
    }
}

extern "C" void kernel_launch(void* const* d_in, const int* in_sizes, int n_in,
                              void* d_out, int out_size, void* d_ws, size_t ws_size,
                              hipStream_t stream) {
    const float* hm  = (const float*)d_in[0];   // (256,256) f32
    const float* pts = (const float*)d_in[1];   // (512,2)  f32
    float* ws  = (float*)d_ws;
    float* out = (float*)d_out;

    // no memset: every ws slot consumed by whd_final is written by whd_main
    whd_main <<<NB_TOTAL, 256, 0, stream>>>(hm, pts, ws);
    whd_final<<<1,        NP,  0, stream>>>(ws, out);
}